// Round 5
// baseline (232.889 us; speedup 1.0000x reference)
//
#include <hip/hip_runtime.h>

// SpatialShiftConvBlock (B=8,T=64,N=21,C=128,F=256), ALL float32:
//   xs[b,t,n,c] = x[b,t,(n - c%21) mod 21, c]       (per-channel circular roll)
//   y  = xs @ W + b                                 (1x1 conv == GEMM K=128)
//   y  = (y - mean)*rsqrt(var + 1e-3)*gamma + beta  (BN training stats over B,T,N)
//   out = relu(y)
//
// R33 == R32 resubmitted (round-4 bench died in infra: "container failed
// twice"; kernel never executed).
// R32 design: W-in-VGPR conv. R31 post-mortem showed the per-c float4 W
// stream was the bottleneck (4B of W per FMA; doubling waves doubled W
// traffic -> regression). New k_conv: one block per bt slab, thread t owns
// channel f=t.
//  - w[128] (W column f) held in VGPRs, loaded once, coalesced: W traffic
//    drops 512MB -> 64MB total.
//  - Re-index by x-row: x[r][c] contributes to out row n=(r+c%21)%21, which is
//    COMPILE-TIME under full unroll -> acc[21] in regs, no LDS in main loop.
//  - x[r][c] is wave-uniform -> scalar loads (s_load), shared via K$ across
//    the block's 4 waves; main loop = 2688 reg-reg FMAs (VALU floor ~4.5us).
//  - __launch_bounds__(256,2): cap 256 VGPR (usage ~170, no spill), grid 512
//    = 2 blocks/CU = 8 waves/CU.
// Harness's 256MiB ws re-poison (fillBufferAligned ~41us) is a fixed tax.

#define NPOS 21
#define CIN  128
#define FOUT 256
#define BT   512            // B*T
#define M_TOTAL 10752       // BT*NPOS
#define BN_EPS 1e-3f

__global__ __launch_bounds__(256, 2) void k_conv(const float* __restrict__ x,
                                                 const float* __restrict__ W,
                                                 const float* __restrict__ bias,
                                                 float* __restrict__ y,
                                                 float* __restrict__ ws)
{
    const int bt = blockIdx.x;
    const int t  = threadIdx.x;            // output channel f = t

    // W column f=t into 128 VGPRs; lane-consecutive addresses -> coalesced.
    float w[CIN];
    #pragma unroll
    for (int c = 0; c < CIN; c++) w[c] = W[c * FOUT + t];

    float acc[NPOS];
    #pragma unroll
    for (int n = 0; n < NPOS; n++) acc[n] = 0.0f;

    const float* __restrict__ xin = x + (size_t)bt * (NPOS * CIN);

    // x[r][c] * w[c] -> acc[(r + c%21) % 21]; r,c fully unrolled so the
    // accumulator index is compile-time. xin[...] is wave-uniform -> s_load.
    #pragma unroll
    for (int r = 0; r < NPOS; r++) {
        const float* __restrict__ xr = xin + r * CIN;
        #pragma unroll
        for (int c = 0; c < CIN; c++) {
            int n = r + (c % NPOS);
            if (n >= NPOS) n -= NPOS;      // compile-time
            acc[n] = fmaf(xr[c], w[c], acc[n]);
        }
    }

    // epilogue: bias, store pre-norm y (coalesced), per-channel partial sums
    const float bv = bias[t];
    float* yout = y + (size_t)bt * (NPOS * FOUT) + t;
    float s = 0.0f, q = 0.0f;
    #pragma unroll
    for (int n = 0; n < NPOS; n++) {
        float o = acc[n] + bv;
        yout[(size_t)n * FOUT] = o;
        s += o;
        q += o * o;
    }
    // channel f=t appears exactly once per block -> direct atomics (512/addr)
    atomicAdd(ws + t, s);
    atomicAdd(ws + FOUT + t, q);
}

__global__ void k_zero(float* __restrict__ ws)
{
    ws[blockIdx.x * 256 + threadIdx.x] = 0.0f;
}

#define BN_BLOCKS 1344      // 1344 * 512 float4 = 688128 = 10752*256/4 exactly

__global__ __launch_bounds__(256) void k_bnapply(float* __restrict__ y,
                                                 const float* __restrict__ ws,
                                                 const float* __restrict__ gamma,
                                                 const float* __restrict__ beta)
{
    const int t  = threadIdx.x;
    const int fb = (t & 63) << 2;          // this thread's fixed channel quad
    const float4 sm = *(const float4*)(ws + fb);
    const float4 sq = *(const float4*)(ws + FOUT + fb);
    const float4 gm = *(const float4*)(gamma + fb);
    const float4 be = *(const float4*)(beta + fb);
    const float invM = 1.0f / (float)M_TOTAL;

    float sc[4], bs[4];
    {
        float m0 = sm.x * invM, m1 = sm.y * invM, m2 = sm.z * invM, m3 = sm.w * invM;
        float v0 = fmaf(-m0, m0, sq.x * invM);
        float v1 = fmaf(-m1, m1, sq.y * invM);
        float v2 = fmaf(-m2, m2, sq.z * invM);
        float v3 = fmaf(-m3, m3, sq.w * invM);
        sc[0] = rsqrtf(v0 + BN_EPS) * gm.x;  bs[0] = be.x - m0 * sc[0];
        sc[1] = rsqrtf(v1 + BN_EPS) * gm.y;  bs[1] = be.y - m1 * sc[1];
        sc[2] = rsqrtf(v2 + BN_EPS) * gm.z;  bs[2] = be.z - m2 * sc[2];
        sc[3] = rsqrtf(v3 + BN_EPS) * gm.w;  bs[3] = be.w - m3 * sc[3];
    }

    float4* y4 = (float4*)y;
    #pragma unroll
    for (int it = 0; it < 2; it++) {
        int g = blockIdx.x * 512 + it * 256 + t;   // g%64 == t&63 -> quad matches fb
        float4 v = y4[g];
        v.x = fmaxf(fmaf(v.x, sc[0], bs[0]), 0.0f);
        v.y = fmaxf(fmaf(v.y, sc[1], bs[1]), 0.0f);
        v.z = fmaxf(fmaf(v.z, sc[2], bs[2]), 0.0f);
        v.w = fmaxf(fmaf(v.w, sc[3], bs[3]), 0.0f);
        y4[g] = v;
    }
}

// Template-named symbol kept defined (harness-compat; not launched).
extern "C" __global__ void SpatialShiftConvBlock_71923522339050_kernel() {}

extern "C" void kernel_launch(void* const* d_in, const int* in_sizes, int n_in,
                              void* d_out, int out_size, void* d_ws, size_t ws_size,
                              hipStream_t stream) {
    float* y  = (float*)d_out;             // FLOAT32 output
    float* ws = (float*)d_ws;              // 512 floats: [sum | sumsq]
    k_zero<<<2, 256, 0, stream>>>(ws);
    k_conv<<<BT, 256, 0, stream>>>((const float*)d_in[0], (const float*)d_in[1],
                                   (const float*)d_in[2], y, ws);
    k_bnapply<<<BN_BLOCKS, 256, 0, stream>>>(y, ws,
                                             (const float*)d_in[3], (const float*)d_in[4]);
}